// Round 13
// baseline (305.405 us; speedup 1.0000x reference)
//
#include <hip/hip_runtime.h>
#include <hip/hip_fp16.h>
#include <cfloat>
#include <cstdint>
#include <cstddef>

#define N_NODES 100000
#define N_EDGES 1600000
#define G_GRAPHS 64
#define BKT_SHIFT 9
#define BKT_NODES (1 << BKT_SHIFT)                              // 512
#define NBKT ((N_NODES + BKT_NODES - 1) >> BKT_SHIFT)           // 196
#define BKT_STRIDE 12288   // fixed staging/CSR slots per bucket (mean 8192)
#define SRC_BITS 17        // N_NODES < 2^17; staging pk = src | (ldst<<17)
#define GAT_WAVES 25000    // N_NODES / GAT_NITER
#define GAT_NITER 4

typedef _Float16 hvec2 __attribute__((ext_vector_type(2)));
typedef _Float16 hvec4 __attribute__((ext_vector_type(4)));
typedef _Float16 hvec8 __attribute__((ext_vector_type(8)));
typedef float f32x4 __attribute__((ext_vector_type(4)));

#define LOG2E 1.4426950408889634f

static __device__ __forceinline__ float fdot2(hvec2 a, hvec2 b, float c) {
#if __has_builtin(__builtin_amdgcn_fdot2)
  return __builtin_amdgcn_fdot2(a, b, c, false);
#else
  return fmaf((float)a.y, (float)b.y, fmaf((float)a.x, (float)b.x, c));
#endif
}

static __device__ __forceinline__ hvec2 leaky2(hvec2 v) {
  return __builtin_elementwise_max(v, v * (_Float16)0.2f);
}

static __device__ __forceinline__ float fast_exp2(float x) {
#if __has_builtin(__builtin_amdgcn_exp2f)
  return __builtin_amdgcn_exp2f(x);
#else
  return exp2f(x);
#endif
}

template <int CTRL>
static __device__ __forceinline__ float dppadd(float v) {
  const int vi = __builtin_bit_cast(int, v);
  const int ti = __builtin_amdgcn_update_dpp(0, vi, CTRL, 0xF, 0xF, true);
  return v + __builtin_bit_cast(float, ti);
}
// allreduce-sum over aligned 8-lane groups (== xor1/xor2/xor4 butterfly)
static __device__ __forceinline__ float dpp_sum8(float v) {
  v = dppadd<0xB1>(v);   // quad_perm [1,0,3,2]  == xor 1
  v = dppadd<0x4E>(v);   // quad_perm [2,3,0,1]  == xor 2
  v = dppadd<0x141>(v);  // row_half_mirror      == xor 4 (quads uniform)
  return v;
}

// ---------------------------------------------------------------------------
// partA: fixed-stride bucket scatter of packed (src | local_dst<<17) ints.
// Also performs fp16 weight prep inline (first 20480 threads, 1 elem each).
// ---------------------------------------------------------------------------
__launch_bounds__(1024) __global__
void partA_kernel(const int* __restrict__ ei, int* __restrict__ bcursor,
                  int* __restrict__ staging,
                  const float* __restrict__ Wl1, const float* __restrict__ Wr1,
                  const float* __restrict__ Wl2, const float* __restrict__ Wr2,
                  __half* __restrict__ Wh1, __half* __restrict__ Wh2) {
  const int tid = threadIdx.x;
  // inline weight prep (independent writes; consumed 2 dispatches later)
  const int widx = blockIdx.x * 1024 + tid;
  if (widx < 2 * 128 * 64) {  // layer 1: Wh1[128][128]
    const int j2 = widx / 128;
    const int k = widx - j2 * 128;
    const int j = (j2 < 64) ? j2 : j2 - 64;
    Wh1[widx] =
        __float2half((j2 < 64) ? Wl1[k * 64 + j] : Wr1[k * 64 + j]);
  } else if (widx < 2 * 128 * 64 + 2 * 64 * 32) {  // layer 2: Wh2[64][64]
    const int i2 = widx - 2 * 128 * 64;
    const int j2 = i2 / 64;
    const int k = i2 - j2 * 64;
    const int j = (j2 < 32) ? j2 : j2 - 32;
    Wh2[i2] = __float2half((j2 < 32) ? Wl2[k * 32 + j] : Wr2[k * 32 + j]);
  }

  __shared__ int lh[NBKT];
  __shared__ int lbase[NBKT];
  for (int i = tid; i < NBKT; i += 1024) lh[i] = 0;
  __syncthreads();
  const int e0 = blockIdx.x * 4096 + tid;
  int pk[4], b[4];
#pragma unroll
  for (int k = 0; k < 4; ++k) {
    const int e = e0 + k * 1024;
    const bool ok = e < N_EDGES;
    const int s = ok ? ei[e] : 0;
    const int d = ok ? ei[N_EDGES + e] : 0;
    pk[k] = s | ((d & (BKT_NODES - 1)) << SRC_BITS);
    b[k] = ok ? (d >> BKT_SHIFT) : -1;
    if (ok) atomicAdd(&lh[b[k]], 1);
  }
  __syncthreads();
  for (int i = tid; i < NBKT; i += 1024) {
    const int c = lh[i];
    lbase[i] = i * BKT_STRIDE + (c ? atomicAdd(&bcursor[i], c) : 0);
    lh[i] = 0;
  }
  __syncthreads();
#pragma unroll
  for (int k = 0; k < 4; ++k) {
    if (b[k] >= 0) {
      const int p = lbase[b[k]] + atomicAdd(&lh[b[k]], 1);
      staging[p] = pk[k];
    }
  }
}

// ---------------------------------------------------------------------------
// Fused partB (blocks 0..NBKT-1) ∥ layer-1 MFMA dual GEMM (remaining blocks).
// ---------------------------------------------------------------------------
#define GEMM1_K 128
#define GEMM1_J 64
#define SMEM_BYTES (64 * (GEMM1_K + 8) * 2 + 2 * GEMM1_J * (GEMM1_K + 8) * 2)

__launch_bounds__(256) __global__
void partB_gemm1_kernel(const int* __restrict__ staging,
                        const int* __restrict__ bcursor,
                        int2* __restrict__ rowdeg, int* __restrict__ csr_src,
                        const float* __restrict__ A,
                        const __half* __restrict__ Wh,
                        __half* __restrict__ O0, __half* __restrict__ O1) {
  __shared__ __align__(16) char smem[SMEM_BYTES];
  const int tid = threadIdx.x;

  if (blockIdx.x < NBKT) {
    // ---------------- partB: per-bucket CSR build ----------------
    int* ldeg = (int*)smem;                   // BKT_NODES ints
    int* lsc = (int*)(smem + BKT_NODES * 4);  // 256 ints
    const int b = blockIdx.x;
    const int node0 = b << BKT_SHIFT;
    const int start = b * BKT_STRIDE;
    const int cnt = bcursor[b];
    if (tid < 64) csr_src[start + cnt + tid] = 0;  // 64-entry pad
    ldeg[2 * tid] = 0;
    ldeg[2 * tid + 1] = 0;
    __syncthreads();
    for (int i = tid; i < cnt; i += 256)
      atomicAdd(&ldeg[staging[start + i] >> SRC_BITS], 1);
    __syncthreads();
    const int d0 = ldeg[2 * tid];
    const int d1 = ldeg[2 * tid + 1];
    const int psum = d0 + d1;
    lsc[tid] = psum;
    __syncthreads();
    for (int d = 1; d < 256; d <<= 1) {
      const int t = (tid >= d) ? lsc[tid - d] : 0;
      __syncthreads();
      lsc[tid] += t;
      __syncthreads();
    }
    const int ex = lsc[tid] - psum + start;  // strided global CSR offset
    const int n0 = node0 + 2 * tid;
    if (n0 < N_NODES)
      *reinterpret_cast<int4*>(&rowdeg[n0]) = make_int4(ex, d0, ex + d0, d1);
    __syncthreads();
    ldeg[2 * tid] = ex;
    ldeg[2 * tid + 1] = ex + d0;
    __syncthreads();
    for (int i = tid; i < cnt; i += 256) {
      const int pk = staging[start + i];
      const int p = atomicAdd(&ldeg[pk >> SRC_BITS], 1);
      csr_src[p] = pk & ((1 << SRC_BITS) - 1);
    }
    return;
  }

  // ---------------- gemm1: O0 = A@Wl (fp16), O1 = A@Wr (fp16) ----------------
  constexpr int K = GEMM1_K;
  constexpr int J = GEMM1_J;
  constexpr int KP = K + 8;
  constexpr int J2 = 2 * J;
  typedef __half(*AldsT)[KP];
  AldsT Alds = (AldsT)smem;                  // [64][KP]
  AldsT Wlds = (AldsT)(smem + 64 * KP * 2);  // [J2][KP]
  const int n0 = (blockIdx.x - NBKT) * 64;

  for (int c = tid; c < J2 * (K / 8); c += 256) {
    const int j = c / (K / 8);
    const int k8 = c - j * (K / 8);
    const uint4 w = reinterpret_cast<const uint4*>(Wh)[c];
    *reinterpret_cast<uint4*>(&Wlds[j][k8 * 8]) = w;
  }
  for (int c = tid; c < 64 * (K / 4); c += 256) {
    const int r = c / (K / 4);
    const int k4 = c - r * (K / 4);
    const int row = n0 + r;
    float4 v = make_float4(0.f, 0.f, 0.f, 0.f);
    if (row < N_NODES)
      v = reinterpret_cast<const float4*>(A)[(size_t)row * (K / 4) + k4];
    const hvec4 h = {(_Float16)v.x, (_Float16)v.y, (_Float16)v.z,
                     (_Float16)v.w};
    *reinterpret_cast<hvec4*>(&Alds[r][k4 * 4]) = h;
  }
  __syncthreads();

  const int wv = tid >> 6;
  const int l = tid & 63;
  const int lr = l & 15;
  const int lk = l >> 4;

  hvec8 afrag[K / 32];
#pragma unroll
  for (int kc = 0; kc < K / 32; ++kc)
    afrag[kc] = *reinterpret_cast<const hvec8*>(
        &Alds[wv * 16 + lr][kc * 32 + 8 * lk]);

#pragma unroll
  for (int jt = 0; jt < J2 / 16; ++jt) {
    f32x4 acc = {0.f, 0.f, 0.f, 0.f};
#pragma unroll
    for (int kc = 0; kc < K / 32; ++kc) {
      const hvec8 b = *reinterpret_cast<const hvec8*>(
          &Wlds[jt * 16 + lr][kc * 32 + 8 * lk]);
      acc = __builtin_amdgcn_mfma_f32_16x16x32_f16(afrag[kc], b, acc, 0, 0, 0);
    }
    const int colt = jt * 16 + lr;
    const int rowb = n0 + wv * 16 + 4 * lk;
#pragma unroll
    for (int r = 0; r < 4; ++r) {
      const int row = rowb + r;
      if (row < N_NODES) {
        if (jt < J / 16)
          O0[(size_t)row * J + colt] = __float2half(acc[r]);
        else
          O1[(size_t)row * J + (colt - J)] = __float2half(acc[r]);
      }
    }
  }
}

// ---------------------------------------------------------------------------
// Layer-2 MFMA dual GEMM (standalone). A input fp16 (agg1h), bias+relu
// fused into staging; both outputs fp16.
// ---------------------------------------------------------------------------
template <int K, int J>
__launch_bounds__(256) __global__
void gemm_mfma2(const __half* __restrict__ Ah, const __half* __restrict__ Wh,
                const float* __restrict__ bias, __half* __restrict__ O0,
                __half* __restrict__ O1) {
  constexpr int KP = K + 8;
  constexpr int J2 = 2 * J;
  __shared__ __align__(16) __half Alds[64][KP];
  __shared__ __align__(16) __half Wlds[J2][KP];
  const int tid = threadIdx.x;
  const int n0 = blockIdx.x * 64;

  for (int c = tid; c < J2 * (K / 8); c += 256) {
    const int j = c / (K / 8);
    const int k8 = c - j * (K / 8);
    const uint4 w = reinterpret_cast<const uint4*>(Wh)[c];
    *reinterpret_cast<uint4*>(&Wlds[j][k8 * 8]) = w;
  }
  for (int c = tid; c < 64 * (K / 4); c += 256) {
    const int r = c / (K / 4);
    const int k4 = c - r * (K / 4);
    const int row = n0 + r;
    hvec4 h = {(_Float16)0.f, (_Float16)0.f, (_Float16)0.f, (_Float16)0.f};
    if (row < N_NODES) {
      const hvec4 a =
          *reinterpret_cast<const hvec4*>(Ah + (size_t)row * K + 4 * k4);
      const float4 b = reinterpret_cast<const float4*>(bias)[k4];
      h.x = (_Float16)fmaxf((float)a.x + b.x, 0.f);
      h.y = (_Float16)fmaxf((float)a.y + b.y, 0.f);
      h.z = (_Float16)fmaxf((float)a.z + b.z, 0.f);
      h.w = (_Float16)fmaxf((float)a.w + b.w, 0.f);
    }
    *reinterpret_cast<hvec4*>(&Alds[r][k4 * 4]) = h;
  }
  __syncthreads();

  const int wv = tid >> 6;
  const int l = tid & 63;
  const int lr = l & 15;
  const int lk = l >> 4;

  hvec8 afrag[K / 32];
#pragma unroll
  for (int kc = 0; kc < K / 32; ++kc)
    afrag[kc] = *reinterpret_cast<const hvec8*>(
        &Alds[wv * 16 + lr][kc * 32 + 8 * lk]);

#pragma unroll
  for (int jt = 0; jt < J2 / 16; ++jt) {
    f32x4 acc = {0.f, 0.f, 0.f, 0.f};
#pragma unroll
    for (int kc = 0; kc < K / 32; ++kc) {
      const hvec8 b = *reinterpret_cast<const hvec8*>(
          &Wlds[jt * 16 + lr][kc * 32 + 8 * lk]);
      acc = __builtin_amdgcn_mfma_f32_16x16x32_f16(afrag[kc], b, acc, 0, 0, 0);
    }
    const int colt = jt * 16 + lr;
    const int rowb = n0 + wv * 16 + 4 * lk;
#pragma unroll
    for (int r = 0; r < 4; ++r) {
      const int row = rowb + r;
      if (row < N_NODES) {
        if (jt < J / 16)
          O0[(size_t)row * J + colt] = __float2half(acc[r]);
        else
          O1[(size_t)row * J + (colt - J)] = __float2half(acc[r]);
      }
    }
  }
}

// ---------------------------------------------------------------------------
// Layer 1 fused softmax-aggregate. H=2, C=32 (64 ch).
// v13: grid-stride waves (4 nodes/wave) with cross-node software pipeline:
// next node's rowdeg/xr/first-group-CSR prefetched during current compute.
// ---------------------------------------------------------------------------
__launch_bounds__(256) __global__
void gat1_kernel(const __half* __restrict__ xlh, const __half* __restrict__ xrh,
                 const float* __restrict__ att, const int2* __restrict__ rowdeg,
                 const int* __restrict__ csr_src, __half* __restrict__ aggh) {
  const int wid = blockIdx.x * 4 + (threadIdx.x >> 6);
  if (wid >= GAT_WAVES) return;
  const int lane = threadIdx.x & 63;
  const int g = lane >> 4;  // edge subgroup 0..3
  const int m = lane & 15;  // channel slice: channels 4m..4m+3 (head = m>>3)
  const float4 atf = *reinterpret_cast<const float4*>(att + 4 * m);
  const hvec2 at01 = {(_Float16)(atf.x * LOG2E), (_Float16)(atf.y * LOG2E)};
  const hvec2 at23 = {(_Float16)(atf.z * LOG2E), (_Float16)(atf.w * LOG2E)};

  auto gather1 = [&](int sel) -> uint2 {
    return *reinterpret_cast<const uint2*>(
        (const char*)xlh + (((size_t)(unsigned)sel) << 7) + 8 * m);
  };

  int n = wid;
  int2 rd = rowdeg[n];
  hvec4 xrv = *reinterpret_cast<const hvec4*>(xrh + ((size_t)n << 6) + 4 * m);
  int r0 = __builtin_amdgcn_readfirstlane(rd.x);
  int dgc = __builtin_amdgcn_readfirstlane(rd.y);
  int sq0[4];
  {
    const int* cp = csr_src + r0 + g;
#pragma unroll
    for (int k = 0; k < 4; ++k) sq0[k] = cp[4 * k];  // pad-safe (<= +51)
  }

#pragma unroll
  for (int it = 0; it < GAT_NITER; ++it) {
    const int rem = dgc;
    const int Kc = (min(rem, 64) + 3) >> 2;  // 1..16 ksteps in chunk 0
    // 1. issue group-0 gathers (CSR indices already resident)
    uint2 B0[4];
#pragma unroll
    for (int k = 0; k < 4; ++k)
      if (k < Kc) B0[k] = gather1(sq0[k]);

    // 2. prefetch next node's rowdeg/xr/first-group CSR (hidden under compute)
    int2 rd_n = rd;
    hvec4 xr_n = xrv;
    int r0_n = r0, dg_n = dgc;
    int sq0_n[4] = {0, 0, 0, 0};
    if (it + 1 < GAT_NITER) {
      const int nn = n + GAT_WAVES;
      rd_n = rowdeg[nn];
      xr_n = *reinterpret_cast<const hvec4*>(xrh + ((size_t)nn << 6) + 4 * m);
      r0_n = __builtin_amdgcn_readfirstlane(rd_n.x);
      dg_n = __builtin_amdgcn_readfirstlane(rd_n.y);
      const int* cpn = csr_src + r0_n + g;
#pragma unroll
      for (int k = 0; k < 4; ++k) sq0_n[k] = cpn[4 * k];  // pad-safe
    }

    // 3. compute
    const hvec2 xh01 = {xrv.x, xrv.y};
    const hvec2 xh23 = {xrv.z, xrv.w};
    float s = 0.f, acc0 = 0.f, acc1 = 0.f, acc2 = 0.f, acc3 = 0.f;
    auto compute1 = [&](int q, uint2 buf, int rm) {
      const hvec2 a01 = __builtin_bit_cast(hvec2, buf.x);
      const hvec2 a23 = __builtin_bit_cast(hvec2, buf.y);
      const hvec2 v01 = leaky2(a01 + xh01);
      const hvec2 v23 = leaky2(a23 + xh23);
      float p = fdot2(v23, at23, fdot2(v01, at01, 0.f));
      p = dpp_sum8(p);
      float e = fast_exp2(p);
      e = (4 * q + g < rm) ? e : 0.f;
      s += e;
      acc0 = fmaf(e, (float)a01.x, acc0);
      acc1 = fmaf(e, (float)a01.y, acc1);
      acc2 = fmaf(e, (float)a23.x, acc2);
      acc3 = fmaf(e, (float)a23.y, acc3);
    };
#pragma unroll
    for (int k = 0; k < 4; ++k)
      if (k < Kc) compute1(k, B0[k], rem);
    // groups 1..3 of chunk 0 (deg > 16)
    {
      const int* cp = csr_src + r0 + g;
#pragma unroll
      for (int g0 = 4; g0 < 16; g0 += 4) {
        if (g0 < Kc) {  // wave-uniform
          int sq[4];
#pragma unroll
          for (int k = 0; k < 4; ++k) sq[k] = cp[4 * (g0 + k)];
          uint2 B[4];
#pragma unroll
          for (int k = 0; k < 4; ++k)
            if (g0 + k < Kc) B[k] = gather1(sq[k]);
#pragma unroll
          for (int k = 0; k < 4; ++k)
            if (g0 + k < Kc) compute1(g0 + k, B[k], rem);
        }
      }
    }
    // chunks beyond 64 edges (deg > 64: vanishingly rare, kept for correctness)
    for (int c0 = 64; c0 < dgc; c0 += 64) {
      const int rem2 = dgc - c0;
      const int* cp = csr_src + r0 + c0 + g;
      const int Kc2 = (min(rem2, 64) + 3) >> 2;
#pragma unroll
      for (int g0 = 0; g0 < 16; g0 += 4) {
        if (g0 < Kc2) {
          int sq[4];
#pragma unroll
          for (int k = 0; k < 4; ++k) sq[k] = cp[4 * (g0 + k)];
          uint2 B[4];
#pragma unroll
          for (int k = 0; k < 4; ++k)
            if (g0 + k < Kc2) B[k] = gather1(sq[k]);
#pragma unroll
          for (int k = 0; k < 4; ++k)
            if (g0 + k < Kc2) compute1(g0 + k, B[k], rem2);
        }
      }
    }

    // merge the 4 edge subgroups + store
    s += __shfl_xor(s, 16);
    s += __shfl_xor(s, 32);
    acc0 += __shfl_xor(acc0, 16);
    acc0 += __shfl_xor(acc0, 32);
    acc1 += __shfl_xor(acc1, 16);
    acc1 += __shfl_xor(acc1, 32);
    acc2 += __shfl_xor(acc2, 16);
    acc2 += __shfl_xor(acc2, 32);
    acc3 += __shfl_xor(acc3, 16);
    acc3 += __shfl_xor(acc3, 32);
    const float inv = s > 0.f ? 1.f / s : 0.f;
    if (g == 0) {
      const hvec4 o = {(_Float16)(acc0 * inv), (_Float16)(acc1 * inv),
                       (_Float16)(acc2 * inv), (_Float16)(acc3 * inv)};
      *reinterpret_cast<hvec4*>(aggh + ((size_t)n << 6) + 4 * m) = o;
    }

    n += GAT_WAVES;
    rd = rd_n;
    xrv = xr_n;
    r0 = r0_n;
    dgc = dg_n;
#pragma unroll
    for (int k = 0; k < 4; ++k) sq0[k] = sq0_n[k];
  }
}

// ---------------------------------------------------------------------------
// Layer 2 fused: H=1, C=32. v13: same cross-node pipeline as gat1.
// ---------------------------------------------------------------------------
__launch_bounds__(256) __global__
void gat2_kernel(const __half* __restrict__ xlh, const __half* __restrict__ xrh,
                 const float* __restrict__ att, const int2* __restrict__ rowdeg,
                 const int* __restrict__ csr_src, const float* __restrict__ b2,
                 float* __restrict__ h2) {
  const int wid = blockIdx.x * 4 + (threadIdx.x >> 6);
  if (wid >= GAT_WAVES) return;
  const int lane = threadIdx.x & 63;
  const int g = lane >> 3;  // edge subgroup 0..7
  const int m = lane & 7;   // channel slice: channels 4m..4m+3
  const float4 atf = *reinterpret_cast<const float4*>(att + 4 * m);
  const hvec2 at01 = {(_Float16)(atf.x * LOG2E), (_Float16)(atf.y * LOG2E)};
  const hvec2 at23 = {(_Float16)(atf.z * LOG2E), (_Float16)(atf.w * LOG2E)};
  const float4 b2v = *reinterpret_cast<const float4*>(b2 + 4 * m);

  auto gather1 = [&](int sel) -> uint2 {
    return *reinterpret_cast<const uint2*>(
        (const char*)xlh + (((size_t)(unsigned)sel) << 6) + 8 * m);
  };

  int n = wid;
  int2 rd = rowdeg[n];
  hvec4 xrv = *reinterpret_cast<const hvec4*>(xrh + (size_t)n * 32 + 4 * m);
  int r0 = __builtin_amdgcn_readfirstlane(rd.x);
  int dgc = __builtin_amdgcn_readfirstlane(rd.y);
  int sq0[4];
  {
    const int* cp = csr_src + r0 + g;
#pragma unroll
    for (int k = 0; k < 4; ++k) sq0[k] = cp[8 * k];  // pad-safe (<= +31)
  }

#pragma unroll
  for (int it = 0; it < GAT_NITER; ++it) {
    const int rem = dgc;
    const int Kc = (min(rem, 64) + 7) >> 3;  // 1..8 ksteps in chunk 0
    // 1. issue group-0 gathers
    uint2 B0[4];
#pragma unroll
    for (int k = 0; k < 4; ++k)
      if (k < Kc) B0[k] = gather1(sq0[k]);

    // 2. prefetch next node
    int2 rd_n = rd;
    hvec4 xr_n = xrv;
    int r0_n = r0, dg_n = dgc;
    int sq0_n[4] = {0, 0, 0, 0};
    if (it + 1 < GAT_NITER) {
      const int nn = n + GAT_WAVES;
      rd_n = rowdeg[nn];
      xr_n = *reinterpret_cast<const hvec4*>(xrh + (size_t)nn * 32 + 4 * m);
      r0_n = __builtin_amdgcn_readfirstlane(rd_n.x);
      dg_n = __builtin_amdgcn_readfirstlane(rd_n.y);
      const int* cpn = csr_src + r0_n + g;
#pragma unroll
      for (int k = 0; k < 4; ++k) sq0_n[k] = cpn[8 * k];  // pad-safe
    }

    // 3. compute
    const hvec2 xh01 = {xrv.x, xrv.y};
    const hvec2 xh23 = {xrv.z, xrv.w};
    float s = 0.f, acc0 = 0.f, acc1 = 0.f, acc2 = 0.f, acc3 = 0.f;
    auto compute1 = [&](int q, uint2 buf, int rm) {
      const hvec2 a01 = __builtin_bit_cast(hvec2, buf.x);
      const hvec2 a23 = __builtin_bit_cast(hvec2, buf.y);
      const hvec2 v01 = leaky2(a01 + xh01);
      const hvec2 v23 = leaky2(a23 + xh23);
      float p = fdot2(v23, at23, fdot2(v01, at01, 0.f));
      p = dpp_sum8(p);
      float e = fast_exp2(p);
      e = (8 * q + g < rm) ? e : 0.f;
      s += e;
      acc0 = fmaf(e, (float)a01.x, acc0);
      acc1 = fmaf(e, (float)a01.y, acc1);
      acc2 = fmaf(e, (float)a23.x, acc2);
      acc3 = fmaf(e, (float)a23.y, acc3);
    };
#pragma unroll
    for (int k = 0; k < 4; ++k)
      if (k < Kc) compute1(k, B0[k], rem);
    // group 1 of chunk 0 (ksteps 4..7, edges 32..63)
    {
      const int* cp = csr_src + r0 + g;
      if (4 < Kc) {
        int sq[4];
#pragma unroll
        for (int k = 0; k < 4; ++k) sq[k] = cp[8 * (4 + k)];
        uint2 B[4];
#pragma unroll
        for (int k = 0; k < 4; ++k)
          if (4 + k < Kc) B[k] = gather1(sq[k]);
#pragma unroll
        for (int k = 0; k < 4; ++k)
          if (4 + k < Kc) compute1(4 + k, B[k], rem);
      }
    }
    // chunks beyond 64 edges (deg > 64: vanishingly rare)
    for (int c0 = 64; c0 < dgc; c0 += 64) {
      const int rem2 = dgc - c0;
      const int* cp = csr_src + r0 + c0 + g;
      const int Kc2 = (min(rem2, 64) + 7) >> 3;
#pragma unroll
      for (int g0 = 0; g0 < 8; g0 += 4) {
        if (g0 < Kc2) {
          int sq[4];
#pragma unroll
          for (int k = 0; k < 4; ++k) sq[k] = cp[8 * (g0 + k)];
          uint2 B[4];
#pragma unroll
          for (int k = 0; k < 4; ++k)
            if (g0 + k < Kc2) B[k] = gather1(sq[k]);
#pragma unroll
          for (int k = 0; k < 4; ++k)
            if (g0 + k < Kc2) compute1(g0 + k, B[k], rem2);
        }
      }
    }

    // merge the 8 edge subgroups + store
    s += __shfl_xor(s, 8);
    s += __shfl_xor(s, 16);
    s += __shfl_xor(s, 32);
    acc0 += __shfl_xor(acc0, 8);
    acc0 += __shfl_xor(acc0, 16);
    acc0 += __shfl_xor(acc0, 32);
    acc1 += __shfl_xor(acc1, 8);
    acc1 += __shfl_xor(acc1, 16);
    acc1 += __shfl_xor(acc1, 32);
    acc2 += __shfl_xor(acc2, 8);
    acc2 += __shfl_xor(acc2, 16);
    acc2 += __shfl_xor(acc2, 32);
    acc3 += __shfl_xor(acc3, 8);
    acc3 += __shfl_xor(acc3, 16);
    acc3 += __shfl_xor(acc3, 32);
    const float inv = s > 0.f ? 1.f / s : 0.f;
    if (g == 0)
      *reinterpret_cast<float4*>(h2 + (size_t)n * 32 + 4 * m) =
          make_float4(fmaxf(fmaf(acc0, inv, b2v.x), 0.f),
                      fmaxf(fmaf(acc1, inv, b2v.y), 0.f),
                      fmaxf(fmaf(acc2, inv, b2v.z), 0.f),
                      fmaxf(fmaf(acc3, inv, b2v.w), 0.f));

    n += GAT_WAVES;
    rd = rd_n;
    xrv = xr_n;
    r0 = r0_n;
    dgc = dg_n;
#pragma unroll
    for (int k = 0; k < 4; ++k) sq0[k] = sq0_n[k];
  }
}

// ---------------------------------------------------------------------------
// Fused gate + pooling (no ticket/fence). LDS-staged h2 tile (128 nodes),
// gate matvec from LDS with float4 ILP; pool via LDS then global atomics.
// ---------------------------------------------------------------------------
__launch_bounds__(256) __global__
void gepool_kernel(const float* __restrict__ h2, const int* __restrict__ batch,
                   const float* __restrict__ g1w, const float* __restrict__ g1b,
                   const float* __restrict__ g2w, const float* __restrict__ g2b,
                   float* __restrict__ gd, float* __restrict__ pooled) {
  __shared__ float Wg[32 * 32];
  __shared__ float Hs[128][32];
  __shared__ float pool[G_GRAPHS * 32];
  __shared__ float gdb[G_GRAPHS];
  const int tid = threadIdx.x;
  for (int i = tid; i < 1024; i += 256) Wg[i] = g1w[i];
  for (int i = tid; i < G_GRAPHS * 32; i += 256) pool[i] = 0.f;
  if (tid < G_GRAPHS) gdb[tid] = 0.f;
  const int start = blockIdx.x * 128;
  // stage h2 tile (coalesced float4)
  for (int i = tid; i < 128 * 8; i += 256) {
    const int n = start + (i >> 3);
    const int q = i & 7;
    float4 v = make_float4(0.f, 0.f, 0.f, 0.f);
    if (n < N_NODES)
      v = reinterpret_cast<const float4*>(h2)[(size_t)n * 8 + q];
    *reinterpret_cast<float4*>(&Hs[i >> 3][q * 4]) = v;
  }
  __syncthreads();
  const int c = tid & 31;
  const int slot = tid >> 5;  // 0..7
  const float g1bc = g1b[c];
  const float g2wc = g2w[c];
  const float g2b0 = g2b[0];
  for (int ln = slot; ln < 128; ln += 8) {
    const int n = start + ln;
    if (n >= N_NODES) break;
    float sg = g1bc;
#pragma unroll
    for (int k4 = 0; k4 < 8; ++k4) {
      const float4 hq = *reinterpret_cast<const float4*>(&Hs[ln][4 * k4]);
      sg = fmaf(hq.x, Wg[(4 * k4 + 0) * 32 + c], sg);
      sg = fmaf(hq.y, Wg[(4 * k4 + 1) * 32 + c], sg);
      sg = fmaf(hq.z, Wg[(4 * k4 + 2) * 32 + c], sg);
      sg = fmaf(hq.w, Wg[(4 * k4 + 3) * 32 + c], sg);
    }
    sg = fmaxf(sg, 0.f);
    float pg = sg * g2wc;
    pg += __shfl_xor(pg, 1);
    pg += __shfl_xor(pg, 2);
    pg += __shfl_xor(pg, 4);
    pg += __shfl_xor(pg, 8);
    pg += __shfl_xor(pg, 16);
    const float ge = __expf(pg + g2b0);
    const int b = batch[n];
    atomicAdd(&pool[b * 32 + c], ge * Hs[ln][c]);
    if (c == 0) atomicAdd(&gdb[b], ge);
  }
  __syncthreads();
  for (int i = tid; i < G_GRAPHS * 32; i += 256)
    if (pool[i] != 0.f) unsafeAtomicAdd(&pooled[i], pool[i]);
  if (tid < G_GRAPHS && gdb[tid] != 0.f) unsafeAtomicAdd(&gd[tid], gdb[tid]);
}

__launch_bounds__(64) __global__
void final_kernel(const float* __restrict__ pooled, const float* __restrict__ gd,
                  const float* __restrict__ l1w, const float* __restrict__ l1b,
                  const float* __restrict__ l2w, const float* __restrict__ l2b,
                  float* __restrict__ out) {
  const int g = blockIdx.x;
  const int lane = threadIdx.x;
  if (lane >= 32) return;
  const float invgd = 1.f / gd[g];
  float s = l1b[lane];
#pragma unroll
  for (int k = 0; k < 32; ++k)
    s = fmaf(pooled[g * 32 + k] * invgd, l1w[k * 32 + lane], s);
  s = fmaxf(s, 0.f);
  float p = s * l2w[lane];
  p += __shfl_xor(p, 1);
  p += __shfl_xor(p, 2);
  p += __shfl_xor(p, 4);
  p += __shfl_xor(p, 8);
  p += __shfl_xor(p, 16);
  if (lane == 0) out[g] = p + l2b[0];
}

// ---------------------------------------------------------------------------
extern "C" void kernel_launch(void* const* d_in, const int* in_sizes, int n_in,
                              void* d_out, int out_size, void* d_ws,
                              size_t ws_size, hipStream_t stream) {
  const float* x    = (const float*)d_in[0];
  const int*   ei   = (const int*)d_in[1];
  const int*   batch= (const int*)d_in[2];
  const float* Wl1  = (const float*)d_in[3];
  const float* Wr1  = (const float*)d_in[4];
  const float* att1 = (const float*)d_in[5];
  const float* b1   = (const float*)d_in[6];
  const float* Wl2  = (const float*)d_in[7];
  const float* Wr2  = (const float*)d_in[8];
  const float* att2 = (const float*)d_in[9];
  const float* b2   = (const float*)d_in[10];
  const float* g1w  = (const float*)d_in[11];
  const float* g1b  = (const float*)d_in[12];
  const float* g2w  = (const float*)d_in[13];
  const float* g2b  = (const float*)d_in[14];
  const float* l1w  = (const float*)d_in[15];
  const float* l1b  = (const float*)d_in[16];
  const float* l2w  = (const float*)d_in[17];
  const float* l2b  = (const float*)d_in[18];
  float* out = (float*)d_out;

  // ---- workspace layout (zero region first: one memset) ----
  int* zbase = (int*)d_ws;                     // 256 ints: bcursor[196]+pad
  int* bcursor = zbase;                        // NBKT
  float* gd = (float*)(zbase + 256);           // 64
  float* pooled = gd + G_GRAPHS;               // 2048
  // zero region total: (256 + 64 + 2048) * 4 = 9472 B
  int2* rowdeg = (int2*)(pooled + G_GRAPHS * 32);          // N int2
  int* csr_src = (int*)(rowdeg + N_NODES);                 // NBKT*BKT_STRIDE
  int* staging = csr_src + (size_t)NBKT * BKT_STRIDE;      // NBKT*BKT_STRIDE
  __half* xr1h = (__half*)(staging + (size_t)NBKT * BKT_STRIDE);  // N*64 half
  __half* agg1h = xr1h + (size_t)N_NODES * 64;             // N*64 half
  __half* Wh1 = agg1h + (size_t)N_NODES * 64;              // [128][128] fp16
  __half* Wh2 = Wh1 + 128 * 128;                           // [64][64] fp16
  __half* xl1h = Wh2 + 64 * 64;                            // N*64 half
  float* h2 = (float*)(xl1h + (size_t)N_NODES * 64);       // N*32 f32
  // layer-2 aliases (stream-ordered producers/consumers)
  __half* xl2h = xl1h;                         // N*32 half
  __half* xr2h = xr1h;                         // N*32 half (region reuse)

  (void)hipMemsetAsync(zbase, 0, (size_t)(256 + 64 + 2048) * sizeof(int),
                       stream);

  // CSR scatter (+ inline fp16 weight prep)
  partA_kernel<<<(N_EDGES + 4095) / 4096, 1024, 0, stream>>>(
      ei, bcursor, staging, Wl1, Wr1, Wl2, Wr2, Wh1, Wh2);

  // partB (CSR finalize) ∥ gemm1 — independent, fused in one launch
  partB_gemm1_kernel<<<NBKT + (N_NODES + 63) / 64, 256, 0, stream>>>(
      staging, bcursor, rowdeg, csr_src, x, Wh1, xl1h, xr1h);

  gat1_kernel<<<(GAT_WAVES + 3) / 4, 256, 0, stream>>>(xl1h, xr1h, att1,
                                                       rowdeg, csr_src, agg1h);

  gemm_mfma2<64, 32><<<(N_NODES + 63) / 64, 256, 0, stream>>>(agg1h, Wh2, b1,
                                                              xl2h, xr2h);
  gat2_kernel<<<(GAT_WAVES + 3) / 4, 256, 0, stream>>>(xl2h, xr2h, att2,
                                                       rowdeg, csr_src, b2, h2);

  gepool_kernel<<<(N_NODES + 127) / 128, 256, 0, stream>>>(
      h2, batch, g1w, g1b, g2w, g2b, gd, pooled);
  final_kernel<<<64, 64, 0, stream>>>(pooled, gd, l1w, l1b, l2w, l2b, out);
}

// Round 14
// 301.079 us; speedup vs baseline: 1.0144x; 1.0144x over previous
//
#include <hip/hip_runtime.h>
#include <hip/hip_fp16.h>
#include <cfloat>
#include <cstdint>
#include <cstddef>

#define N_NODES 100000
#define N_EDGES 1600000
#define G_GRAPHS 64
#define BKT_SHIFT 9
#define BKT_NODES (1 << BKT_SHIFT)                              // 512
#define NBKT ((N_NODES + BKT_NODES - 1) >> BKT_SHIFT)           // 196
#define BKT_STRIDE 12288   // fixed staging/CSR slots per bucket (mean 8192)
#define SRC_BITS 17        // N_NODES < 2^17; staging pk = src | (ldst<<17)

typedef _Float16 hvec2 __attribute__((ext_vector_type(2)));
typedef _Float16 hvec4 __attribute__((ext_vector_type(4)));
typedef _Float16 hvec8 __attribute__((ext_vector_type(8)));
typedef float f32x4 __attribute__((ext_vector_type(4)));

#define LOG2E 1.4426950408889634f

static __device__ __forceinline__ float fdot2(hvec2 a, hvec2 b, float c) {
#if __has_builtin(__builtin_amdgcn_fdot2)
  return __builtin_amdgcn_fdot2(a, b, c, false);
#else
  return fmaf((float)a.y, (float)b.y, fmaf((float)a.x, (float)b.x, c));
#endif
}

static __device__ __forceinline__ hvec2 leaky2(hvec2 v) {
  return __builtin_elementwise_max(v, v * (_Float16)0.2f);
}

static __device__ __forceinline__ float fast_exp2(float x) {
#if __has_builtin(__builtin_amdgcn_exp2f)
  return __builtin_amdgcn_exp2f(x);
#else
  return exp2f(x);
#endif
}

template <int CTRL>
static __device__ __forceinline__ float dppadd(float v) {
  const int vi = __builtin_bit_cast(int, v);
  const int ti = __builtin_amdgcn_update_dpp(0, vi, CTRL, 0xF, 0xF, true);
  return v + __builtin_bit_cast(float, ti);
}
// allreduce-sum over aligned 8-lane groups (== xor1/xor2/xor4 butterfly)
static __device__ __forceinline__ float dpp_sum8(float v) {
  v = dppadd<0xB1>(v);   // quad_perm [1,0,3,2]  == xor 1
  v = dppadd<0x4E>(v);   // quad_perm [2,3,0,1]  == xor 2
  v = dppadd<0x141>(v);  // row_half_mirror      == xor 4 (quads uniform)
  return v;
}

// ---------------------------------------------------------------------------
// partA: fixed-stride bucket scatter of packed (src | local_dst<<17) ints.
// Also performs fp16 weight prep inline (first 20480 threads, 1 elem each).
// ---------------------------------------------------------------------------
__launch_bounds__(1024) __global__
void partA_kernel(const int* __restrict__ ei, int* __restrict__ bcursor,
                  int* __restrict__ staging,
                  const float* __restrict__ Wl1, const float* __restrict__ Wr1,
                  const float* __restrict__ Wl2, const float* __restrict__ Wr2,
                  __half* __restrict__ Wh1, __half* __restrict__ Wh2) {
  const int tid = threadIdx.x;
  // inline weight prep (independent writes; consumed 2 dispatches later)
  const int widx = blockIdx.x * 1024 + tid;
  if (widx < 2 * 128 * 64) {  // layer 1: Wh1[128][128]
    const int j2 = widx / 128;
    const int k = widx - j2 * 128;
    const int j = (j2 < 64) ? j2 : j2 - 64;
    Wh1[widx] =
        __float2half((j2 < 64) ? Wl1[k * 64 + j] : Wr1[k * 64 + j]);
  } else if (widx < 2 * 128 * 64 + 2 * 64 * 32) {  // layer 2: Wh2[64][64]
    const int i2 = widx - 2 * 128 * 64;
    const int j2 = i2 / 64;
    const int k = i2 - j2 * 64;
    const int j = (j2 < 32) ? j2 : j2 - 32;
    Wh2[i2] = __float2half((j2 < 32) ? Wl2[k * 32 + j] : Wr2[k * 32 + j]);
  }

  __shared__ int lh[NBKT];
  __shared__ int lbase[NBKT];
  for (int i = tid; i < NBKT; i += 1024) lh[i] = 0;
  __syncthreads();
  const int e0 = blockIdx.x * 4096 + tid;
  int pk[4], b[4];
#pragma unroll
  for (int k = 0; k < 4; ++k) {
    const int e = e0 + k * 1024;
    const bool ok = e < N_EDGES;
    const int s = ok ? ei[e] : 0;
    const int d = ok ? ei[N_EDGES + e] : 0;
    pk[k] = s | ((d & (BKT_NODES - 1)) << SRC_BITS);
    b[k] = ok ? (d >> BKT_SHIFT) : -1;
    if (ok) atomicAdd(&lh[b[k]], 1);
  }
  __syncthreads();
  for (int i = tid; i < NBKT; i += 1024) {
    const int c = lh[i];
    lbase[i] = i * BKT_STRIDE + (c ? atomicAdd(&bcursor[i], c) : 0);
    lh[i] = 0;
  }
  __syncthreads();
#pragma unroll
  for (int k = 0; k < 4; ++k) {
    if (b[k] >= 0) {
      const int p = lbase[b[k]] + atomicAdd(&lh[b[k]], 1);
      staging[p] = pk[k];
    }
  }
}

// ---------------------------------------------------------------------------
// Fused partB (blocks 0..NBKT-1) ∥ layer-1 MFMA dual GEMM (remaining blocks).
// Both GEMM outputs fp16 (consumers round to fp16 anyway).
// ---------------------------------------------------------------------------
#define GEMM1_K 128
#define GEMM1_J 64
#define SMEM_BYTES (64 * (GEMM1_K + 8) * 2 + 2 * GEMM1_J * (GEMM1_K + 8) * 2)

__launch_bounds__(256) __global__
void partB_gemm1_kernel(const int* __restrict__ staging,
                        const int* __restrict__ bcursor,
                        int2* __restrict__ rowdeg, int* __restrict__ csr_src,
                        const float* __restrict__ A,
                        const __half* __restrict__ Wh,
                        __half* __restrict__ O0, __half* __restrict__ O1) {
  __shared__ __align__(16) char smem[SMEM_BYTES];
  const int tid = threadIdx.x;

  if (blockIdx.x < NBKT) {
    // ---------------- partB: per-bucket CSR build ----------------
    int* ldeg = (int*)smem;                   // BKT_NODES ints
    int* lsc = (int*)(smem + BKT_NODES * 4);  // 256 ints
    const int b = blockIdx.x;
    const int node0 = b << BKT_SHIFT;
    const int start = b * BKT_STRIDE;
    const int cnt = bcursor[b];
    if (tid < 64) csr_src[start + cnt + tid] = 0;  // 64-entry pad
    ldeg[2 * tid] = 0;
    ldeg[2 * tid + 1] = 0;
    __syncthreads();
    for (int i = tid; i < cnt; i += 256)
      atomicAdd(&ldeg[staging[start + i] >> SRC_BITS], 1);
    __syncthreads();
    const int d0 = ldeg[2 * tid];
    const int d1 = ldeg[2 * tid + 1];
    const int psum = d0 + d1;
    lsc[tid] = psum;
    __syncthreads();
    for (int d = 1; d < 256; d <<= 1) {
      const int t = (tid >= d) ? lsc[tid - d] : 0;
      __syncthreads();
      lsc[tid] += t;
      __syncthreads();
    }
    const int ex = lsc[tid] - psum + start;  // strided global CSR offset
    const int n0 = node0 + 2 * tid;
    if (n0 < N_NODES)
      *reinterpret_cast<int4*>(&rowdeg[n0]) = make_int4(ex, d0, ex + d0, d1);
    __syncthreads();
    ldeg[2 * tid] = ex;
    ldeg[2 * tid + 1] = ex + d0;
    __syncthreads();
    for (int i = tid; i < cnt; i += 256) {
      const int pk = staging[start + i];
      const int p = atomicAdd(&ldeg[pk >> SRC_BITS], 1);
      csr_src[p] = pk & ((1 << SRC_BITS) - 1);
    }
    return;
  }

  // ---------------- gemm1: O0 = A@Wl (fp16), O1 = A@Wr (fp16) ----------------
  constexpr int K = GEMM1_K;
  constexpr int J = GEMM1_J;
  constexpr int KP = K + 8;
  constexpr int J2 = 2 * J;
  typedef __half(*AldsT)[KP];
  AldsT Alds = (AldsT)smem;                  // [64][KP]
  AldsT Wlds = (AldsT)(smem + 64 * KP * 2);  // [J2][KP]
  const int n0 = (blockIdx.x - NBKT) * 64;

  for (int c = tid; c < J2 * (K / 8); c += 256) {
    const int j = c / (K / 8);
    const int k8 = c - j * (K / 8);
    const uint4 w = reinterpret_cast<const uint4*>(Wh)[c];
    *reinterpret_cast<uint4*>(&Wlds[j][k8 * 8]) = w;
  }
  for (int c = tid; c < 64 * (K / 4); c += 256) {
    const int r = c / (K / 4);
    const int k4 = c - r * (K / 4);
    const int row = n0 + r;
    float4 v = make_float4(0.f, 0.f, 0.f, 0.f);
    if (row < N_NODES)
      v = reinterpret_cast<const float4*>(A)[(size_t)row * (K / 4) + k4];
    const hvec4 h = {(_Float16)v.x, (_Float16)v.y, (_Float16)v.z,
                     (_Float16)v.w};
    *reinterpret_cast<hvec4*>(&Alds[r][k4 * 4]) = h;
  }
  __syncthreads();

  const int wv = tid >> 6;
  const int l = tid & 63;
  const int lr = l & 15;
  const int lk = l >> 4;

  hvec8 afrag[K / 32];
#pragma unroll
  for (int kc = 0; kc < K / 32; ++kc)
    afrag[kc] = *reinterpret_cast<const hvec8*>(
        &Alds[wv * 16 + lr][kc * 32 + 8 * lk]);

#pragma unroll
  for (int jt = 0; jt < J2 / 16; ++jt) {
    f32x4 acc = {0.f, 0.f, 0.f, 0.f};
#pragma unroll
    for (int kc = 0; kc < K / 32; ++kc) {
      const hvec8 b = *reinterpret_cast<const hvec8*>(
          &Wlds[jt * 16 + lr][kc * 32 + 8 * lk]);
      acc = __builtin_amdgcn_mfma_f32_16x16x32_f16(afrag[kc], b, acc, 0, 0, 0);
    }
    const int colt = jt * 16 + lr;
    const int rowb = n0 + wv * 16 + 4 * lk;
#pragma unroll
    for (int r = 0; r < 4; ++r) {
      const int row = rowb + r;
      if (row < N_NODES) {
        if (jt < J / 16)
          O0[(size_t)row * J + colt] = __float2half(acc[r]);
        else
          O1[(size_t)row * J + (colt - J)] = __float2half(acc[r]);
      }
    }
  }
}

// ---------------------------------------------------------------------------
// Layer-2 MFMA dual GEMM (standalone). A input fp16 (agg1h), bias+relu
// fused into staging; both outputs fp16.
// ---------------------------------------------------------------------------
template <int K, int J>
__launch_bounds__(256) __global__
void gemm_mfma2(const __half* __restrict__ Ah, const __half* __restrict__ Wh,
                const float* __restrict__ bias, __half* __restrict__ O0,
                __half* __restrict__ O1) {
  constexpr int KP = K + 8;
  constexpr int J2 = 2 * J;
  __shared__ __align__(16) __half Alds[64][KP];
  __shared__ __align__(16) __half Wlds[J2][KP];
  const int tid = threadIdx.x;
  const int n0 = blockIdx.x * 64;

  for (int c = tid; c < J2 * (K / 8); c += 256) {
    const int j = c / (K / 8);
    const int k8 = c - j * (K / 8);
    const uint4 w = reinterpret_cast<const uint4*>(Wh)[c];
    *reinterpret_cast<uint4*>(&Wlds[j][k8 * 8]) = w;
  }
  for (int c = tid; c < 64 * (K / 4); c += 256) {
    const int r = c / (K / 4);
    const int k4 = c - r * (K / 4);
    const int row = n0 + r;
    hvec4 h = {(_Float16)0.f, (_Float16)0.f, (_Float16)0.f, (_Float16)0.f};
    if (row < N_NODES) {
      const hvec4 a =
          *reinterpret_cast<const hvec4*>(Ah + (size_t)row * K + 4 * k4);
      const float4 b = reinterpret_cast<const float4*>(bias)[k4];
      h.x = (_Float16)fmaxf((float)a.x + b.x, 0.f);
      h.y = (_Float16)fmaxf((float)a.y + b.y, 0.f);
      h.z = (_Float16)fmaxf((float)a.z + b.z, 0.f);
      h.w = (_Float16)fmaxf((float)a.w + b.w, 0.f);
    }
    *reinterpret_cast<hvec4*>(&Alds[r][k4 * 4]) = h;
  }
  __syncthreads();

  const int wv = tid >> 6;
  const int l = tid & 63;
  const int lr = l & 15;
  const int lk = l >> 4;

  hvec8 afrag[K / 32];
#pragma unroll
  for (int kc = 0; kc < K / 32; ++kc)
    afrag[kc] = *reinterpret_cast<const hvec8*>(
        &Alds[wv * 16 + lr][kc * 32 + 8 * lk]);

#pragma unroll
  for (int jt = 0; jt < J2 / 16; ++jt) {
    f32x4 acc = {0.f, 0.f, 0.f, 0.f};
#pragma unroll
    for (int kc = 0; kc < K / 32; ++kc) {
      const hvec8 b = *reinterpret_cast<const hvec8*>(
          &Wlds[jt * 16 + lr][kc * 32 + 8 * lk]);
      acc = __builtin_amdgcn_mfma_f32_16x16x32_f16(afrag[kc], b, acc, 0, 0, 0);
    }
    const int colt = jt * 16 + lr;
    const int rowb = n0 + wv * 16 + 4 * lk;
#pragma unroll
    for (int r = 0; r < 4; ++r) {
      const int row = rowb + r;
      if (row < N_NODES) {
        if (jt < J / 16)
          O0[(size_t)row * J + colt] = __float2half(acc[r]);
        else
          O1[(size_t)row * J + (colt - J)] = __float2half(acc[r]);
      }
    }
  }
}

// ---------------------------------------------------------------------------
// Layer 1 fused softmax-aggregate. H=2, C=32 (64 ch). One wave per node.
// xr input fp16, agg output fp16. (v12 structure — measured best.)
// ---------------------------------------------------------------------------
__launch_bounds__(256) __global__
void gat1_kernel(const __half* __restrict__ xlh, const __half* __restrict__ xrh,
                 const float* __restrict__ att, const int2* __restrict__ rowdeg,
                 const int* __restrict__ csr_src, __half* __restrict__ aggh) {
  const int n =
      __builtin_amdgcn_readfirstlane(blockIdx.x * 4 + (threadIdx.x >> 6));
  if (n >= N_NODES) return;
  const int lane = threadIdx.x & 63;
  const int g = lane >> 4;  // edge subgroup 0..3
  const int m = lane & 15;  // channel slice: channels 4m..4m+3 (head = m>>3)
  const int2 rd = rowdeg[n];
  const int r0 = __builtin_amdgcn_readfirstlane(rd.x);
  const int dg = __builtin_amdgcn_readfirstlane(rd.y);

  const hvec4 xrv =
      *reinterpret_cast<const hvec4*>(xrh + ((size_t)n << 6) + 4 * m);
  const hvec2 xh01 = {xrv.x, xrv.y};
  const hvec2 xh23 = {xrv.z, xrv.w};
  const float4 atf = *reinterpret_cast<const float4*>(att + 4 * m);
  const hvec2 at01 = {(_Float16)(atf.x * LOG2E), (_Float16)(atf.y * LOG2E)};
  const hvec2 at23 = {(_Float16)(atf.z * LOG2E), (_Float16)(atf.w * LOG2E)};

  float s = 0.f, acc0 = 0.f, acc1 = 0.f, acc2 = 0.f, acc3 = 0.f;

  auto gather1 = [&](int sel) -> uint2 {
    return *reinterpret_cast<const uint2*>(
        (const char*)xlh + (((size_t)(unsigned)sel) << 7) + 8 * m);
  };
  auto compute1 = [&](int q, uint2 buf, int rem) {
    const hvec2 a01 = __builtin_bit_cast(hvec2, buf.x);
    const hvec2 a23 = __builtin_bit_cast(hvec2, buf.y);
    const hvec2 v01 = leaky2(a01 + xh01);
    const hvec2 v23 = leaky2(a23 + xh23);
    float p = fdot2(v23, at23, fdot2(v01, at01, 0.f));
    p = dpp_sum8(p);
    float e = fast_exp2(p);
    e = (4 * q + g < rem) ? e : 0.f;
    s += e;
    acc0 = fmaf(e, (float)a01.x, acc0);
    acc1 = fmaf(e, (float)a01.y, acc1);
    acc2 = fmaf(e, (float)a23.x, acc2);
    acc3 = fmaf(e, (float)a23.y, acc3);
  };

  for (int c0 = 0; c0 < dg; c0 += 64) {
    const int rem = dg - c0;
    const int* cp = csr_src + r0 + c0 + (lane >> 4);
    const int Kc = (min(rem, 64) + 3) >> 2;  // 1..16 ksteps
#pragma unroll
    for (int g0 = 0; g0 < 16; g0 += 4) {
      if (g0 < Kc) {  // wave-uniform
        int sq[4];
#pragma unroll
        for (int k = 0; k < 4; ++k) sq[k] = cp[4 * (g0 + k)];  // pad-safe
        uint2 B[4];
#pragma unroll
        for (int k = 0; k < 4; ++k)
          if (g0 + k < Kc) B[k] = gather1(sq[k]);
#pragma unroll
        for (int k = 0; k < 4; ++k)
          if (g0 + k < Kc) compute1(g0 + k, B[k], rem);
      }
    }
  }

  s += __shfl_xor(s, 16);
  s += __shfl_xor(s, 32);
  acc0 += __shfl_xor(acc0, 16);
  acc0 += __shfl_xor(acc0, 32);
  acc1 += __shfl_xor(acc1, 16);
  acc1 += __shfl_xor(acc1, 32);
  acc2 += __shfl_xor(acc2, 16);
  acc2 += __shfl_xor(acc2, 32);
  acc3 += __shfl_xor(acc3, 16);
  acc3 += __shfl_xor(acc3, 32);
  const float inv = s > 0.f ? 1.f / s : 0.f;
  if (g == 0) {
    const hvec4 o = {(_Float16)(acc0 * inv), (_Float16)(acc1 * inv),
                     (_Float16)(acc2 * inv), (_Float16)(acc3 * inv)};
    *reinterpret_cast<hvec4*>(aggh + ((size_t)n << 6) + 4 * m) = o;
  }
}

// ---------------------------------------------------------------------------
// Layer 2 fused: H=1, C=32. xr input fp16. (v12 structure.)
// ---------------------------------------------------------------------------
__launch_bounds__(256) __global__
void gat2_kernel(const __half* __restrict__ xlh, const __half* __restrict__ xrh,
                 const float* __restrict__ att, const int2* __restrict__ rowdeg,
                 const int* __restrict__ csr_src, const float* __restrict__ b2,
                 float* __restrict__ h2) {
  const int n =
      __builtin_amdgcn_readfirstlane(blockIdx.x * 4 + (threadIdx.x >> 6));
  if (n >= N_NODES) return;
  const int lane = threadIdx.x & 63;
  const int g = lane >> 3;  // edge subgroup 0..7
  const int m = lane & 7;   // channel slice: channels 4m..4m+3
  const int2 rd = rowdeg[n];
  const int r0 = __builtin_amdgcn_readfirstlane(rd.x);
  const int dg = __builtin_amdgcn_readfirstlane(rd.y);

  const hvec4 xrv =
      *reinterpret_cast<const hvec4*>(xrh + (size_t)n * 32 + 4 * m);
  const hvec2 xh01 = {xrv.x, xrv.y};
  const hvec2 xh23 = {xrv.z, xrv.w};
  const float4 atf = *reinterpret_cast<const float4*>(att + 4 * m);
  const hvec2 at01 = {(_Float16)(atf.x * LOG2E), (_Float16)(atf.y * LOG2E)};
  const hvec2 at23 = {(_Float16)(atf.z * LOG2E), (_Float16)(atf.w * LOG2E)};

  float s = 0.f, acc0 = 0.f, acc1 = 0.f, acc2 = 0.f, acc3 = 0.f;

  auto gather1 = [&](int sel) -> uint2 {
    return *reinterpret_cast<const uint2*>(
        (const char*)xlh + (((size_t)(unsigned)sel) << 6) + 8 * m);
  };
  auto compute1 = [&](int q, uint2 buf, int rem) {
    const hvec2 a01 = __builtin_bit_cast(hvec2, buf.x);
    const hvec2 a23 = __builtin_bit_cast(hvec2, buf.y);
    const hvec2 v01 = leaky2(a01 + xh01);
    const hvec2 v23 = leaky2(a23 + xh23);
    float p = fdot2(v23, at23, fdot2(v01, at01, 0.f));
    p = dpp_sum8(p);
    float e = fast_exp2(p);
    e = (8 * q + g < rem) ? e : 0.f;
    s += e;
    acc0 = fmaf(e, (float)a01.x, acc0);
    acc1 = fmaf(e, (float)a01.y, acc1);
    acc2 = fmaf(e, (float)a23.x, acc2);
    acc3 = fmaf(e, (float)a23.y, acc3);
  };

  for (int c0 = 0; c0 < dg; c0 += 64) {
    const int rem = dg - c0;
    const int* cp = csr_src + r0 + c0 + (lane >> 3);
    const int Kc = (min(rem, 64) + 7) >> 3;  // 1..8 ksteps
#pragma unroll
    for (int g0 = 0; g0 < 8; g0 += 4) {
      if (g0 < Kc) {  // wave-uniform
        int sq[4];
#pragma unroll
        for (int k = 0; k < 4; ++k) sq[k] = cp[8 * (g0 + k)];  // pad-safe
        uint2 B[4];
#pragma unroll
        for (int k = 0; k < 4; ++k)
          if (g0 + k < Kc) B[k] = gather1(sq[k]);
#pragma unroll
        for (int k = 0; k < 4; ++k)
          if (g0 + k < Kc) compute1(g0 + k, B[k], rem);
      }
    }
  }

  s += __shfl_xor(s, 8);
  s += __shfl_xor(s, 16);
  s += __shfl_xor(s, 32);
  acc0 += __shfl_xor(acc0, 8);
  acc0 += __shfl_xor(acc0, 16);
  acc0 += __shfl_xor(acc0, 32);
  acc1 += __shfl_xor(acc1, 8);
  acc1 += __shfl_xor(acc1, 16);
  acc1 += __shfl_xor(acc1, 32);
  acc2 += __shfl_xor(acc2, 8);
  acc2 += __shfl_xor(acc2, 16);
  acc2 += __shfl_xor(acc2, 32);
  acc3 += __shfl_xor(acc3, 8);
  acc3 += __shfl_xor(acc3, 16);
  acc3 += __shfl_xor(acc3, 32);
  const float inv = s > 0.f ? 1.f / s : 0.f;
  const float4 b2v = *reinterpret_cast<const float4*>(b2 + 4 * m);
  if (g == 0)
    *reinterpret_cast<float4*>(h2 + (size_t)n * 32 + 4 * m) =
        make_float4(fmaxf(fmaf(acc0, inv, b2v.x), 0.f),
                    fmaxf(fmaf(acc1, inv, b2v.y), 0.f),
                    fmaxf(fmaf(acc2, inv, b2v.z), 0.f),
                    fmaxf(fmaf(acc3, inv, b2v.w), 0.f));
}

// ---------------------------------------------------------------------------
// Fused gate + pooling (no ticket/fence). LDS-staged h2 tile (128 nodes),
// gate matvec from LDS with float4 ILP; pool via LDS then global atomics.
// ---------------------------------------------------------------------------
__launch_bounds__(256) __global__
void gepool_kernel(const float* __restrict__ h2, const int* __restrict__ batch,
                   const float* __restrict__ g1w, const float* __restrict__ g1b,
                   const float* __restrict__ g2w, const float* __restrict__ g2b,
                   float* __restrict__ gd, float* __restrict__ pooled) {
  __shared__ float Wg[32 * 32];
  __shared__ float Hs[128][32];
  __shared__ float pool[G_GRAPHS * 32];
  __shared__ float gdb[G_GRAPHS];
  const int tid = threadIdx.x;
  for (int i = tid; i < 1024; i += 256) Wg[i] = g1w[i];
  for (int i = tid; i < G_GRAPHS * 32; i += 256) pool[i] = 0.f;
  if (tid < G_GRAPHS) gdb[tid] = 0.f;
  const int start = blockIdx.x * 128;
  // stage h2 tile (coalesced float4)
  for (int i = tid; i < 128 * 8; i += 256) {
    const int n = start + (i >> 3);
    const int q = i & 7;
    float4 v = make_float4(0.f, 0.f, 0.f, 0.f);
    if (n < N_NODES)
      v = reinterpret_cast<const float4*>(h2)[(size_t)n * 8 + q];
    *reinterpret_cast<float4*>(&Hs[i >> 3][q * 4]) = v;
  }
  __syncthreads();
  const int c = tid & 31;
  const int slot = tid >> 5;  // 0..7
  const float g1bc = g1b[c];
  const float g2wc = g2w[c];
  const float g2b0 = g2b[0];
  for (int ln = slot; ln < 128; ln += 8) {
    const int n = start + ln;
    if (n >= N_NODES) break;
    float sg = g1bc;
#pragma unroll
    for (int k4 = 0; k4 < 8; ++k4) {
      const float4 hq = *reinterpret_cast<const float4*>(&Hs[ln][4 * k4]);
      sg = fmaf(hq.x, Wg[(4 * k4 + 0) * 32 + c], sg);
      sg = fmaf(hq.y, Wg[(4 * k4 + 1) * 32 + c], sg);
      sg = fmaf(hq.z, Wg[(4 * k4 + 2) * 32 + c], sg);
      sg = fmaf(hq.w, Wg[(4 * k4 + 3) * 32 + c], sg);
    }
    sg = fmaxf(sg, 0.f);
    float pg = sg * g2wc;
    pg += __shfl_xor(pg, 1);
    pg += __shfl_xor(pg, 2);
    pg += __shfl_xor(pg, 4);
    pg += __shfl_xor(pg, 8);
    pg += __shfl_xor(pg, 16);
    const float ge = __expf(pg + g2b0);
    const int b = batch[n];
    atomicAdd(&pool[b * 32 + c], ge * Hs[ln][c]);
    if (c == 0) atomicAdd(&gdb[b], ge);
  }
  __syncthreads();
  for (int i = tid; i < G_GRAPHS * 32; i += 256)
    if (pool[i] != 0.f) unsafeAtomicAdd(&pooled[i], pool[i]);
  if (tid < G_GRAPHS && gdb[tid] != 0.f) unsafeAtomicAdd(&gd[tid], gdb[tid]);
}

__launch_bounds__(64) __global__
void final_kernel(const float* __restrict__ pooled, const float* __restrict__ gd,
                  const float* __restrict__ l1w, const float* __restrict__ l1b,
                  const float* __restrict__ l2w, const float* __restrict__ l2b,
                  float* __restrict__ out) {
  const int g = blockIdx.x;
  const int lane = threadIdx.x;
  if (lane >= 32) return;
  const float invgd = 1.f / gd[g];
  float s = l1b[lane];
#pragma unroll
  for (int k = 0; k < 32; ++k)
    s = fmaf(pooled[g * 32 + k] * invgd, l1w[k * 32 + lane], s);
  s = fmaxf(s, 0.f);
  float p = s * l2w[lane];
  p += __shfl_xor(p, 1);
  p += __shfl_xor(p, 2);
  p += __shfl_xor(p, 4);
  p += __shfl_xor(p, 8);
  p += __shfl_xor(p, 16);
  if (lane == 0) out[g] = p + l2b[0];
}

// ---------------------------------------------------------------------------
extern "C" void kernel_launch(void* const* d_in, const int* in_sizes, int n_in,
                              void* d_out, int out_size, void* d_ws,
                              size_t ws_size, hipStream_t stream) {
  const float* x    = (const float*)d_in[0];
  const int*   ei   = (const int*)d_in[1];
  const int*   batch= (const int*)d_in[2];
  const float* Wl1  = (const float*)d_in[3];
  const float* Wr1  = (const float*)d_in[4];
  const float* att1 = (const float*)d_in[5];
  const float* b1   = (const float*)d_in[6];
  const float* Wl2  = (const float*)d_in[7];
  const float* Wr2  = (const float*)d_in[8];
  const float* att2 = (const float*)d_in[9];
  const float* b2   = (const float*)d_in[10];
  const float* g1w  = (const float*)d_in[11];
  const float* g1b  = (const float*)d_in[12];
  const float* g2w  = (const float*)d_in[13];
  const float* g2b  = (const float*)d_in[14];
  const float* l1w  = (const float*)d_in[15];
  const float* l1b  = (const float*)d_in[16];
  const float* l2w  = (const float*)d_in[17];
  const float* l2b  = (const float*)d_in[18];
  float* out = (float*)d_out;

  // ---- workspace layout (zero region first: one memset) ----
  int* zbase = (int*)d_ws;                     // 256 ints: bcursor[196]+pad
  int* bcursor = zbase;                        // NBKT
  float* gd = (float*)(zbase + 256);           // 64
  float* pooled = gd + G_GRAPHS;               // 2048
  // zero region total: (256 + 64 + 2048) * 4 = 9472 B
  int2* rowdeg = (int2*)(pooled + G_GRAPHS * 32);          // N int2
  int* csr_src = (int*)(rowdeg + N_NODES);                 // NBKT*BKT_STRIDE
  int* staging = csr_src + (size_t)NBKT * BKT_STRIDE;      // NBKT*BKT_STRIDE
  __half* xr1h = (__half*)(staging + (size_t)NBKT * BKT_STRIDE);  // N*64 half
  __half* agg1h = xr1h + (size_t)N_NODES * 64;             // N*64 half
  __half* Wh1 = agg1h + (size_t)N_NODES * 64;              // [128][128] fp16
  __half* Wh2 = Wh1 + 128 * 128;                           // [64][64] fp16
  __half* xl1h = Wh2 + 64 * 64;                            // N*64 half
  float* h2 = (float*)(xl1h + (size_t)N_NODES * 64);       // N*32 f32
  // layer-2 aliases (stream-ordered producers/consumers)
  __half* xl2h = xl1h;                         // N*32 half
  __half* xr2h = xr1h;                         // N*32 half (region reuse)

  (void)hipMemsetAsync(zbase, 0, (size_t)(256 + 64 + 2048) * sizeof(int),
                       stream);

  // CSR scatter (+ inline fp16 weight prep)
  partA_kernel<<<(N_EDGES + 4095) / 4096, 1024, 0, stream>>>(
      ei, bcursor, staging, Wl1, Wr1, Wl2, Wr2, Wh1, Wh2);

  // partB (CSR finalize) ∥ gemm1 — independent, fused in one launch
  partB_gemm1_kernel<<<NBKT + (N_NODES + 63) / 64, 256, 0, stream>>>(
      staging, bcursor, rowdeg, csr_src, x, Wh1, xl1h, xr1h);

  gat1_kernel<<<(N_NODES + 3) / 4, 256, 0, stream>>>(xl1h, xr1h, att1, rowdeg,
                                                     csr_src, agg1h);

  gemm_mfma2<64, 32><<<(N_NODES + 63) / 64, 256, 0, stream>>>(agg1h, Wh2, b1,
                                                              xl2h, xr2h);
  gat2_kernel<<<(N_NODES + 3) / 4, 256, 0, stream>>>(xl2h, xr2h, att2, rowdeg,
                                                     csr_src, b2, h2);

  gepool_kernel<<<(N_NODES + 127) / 128, 256, 0, stream>>>(
      h2, batch, g1w, g1b, g2w, g2b, gd, pooled);
  final_kernel<<<64, 64, 0, stream>>>(pooled, gd, l1w, l1b, l2w, l2b, out);
}